// Round 2
// baseline (190.711 us; speedup 1.0000x reference)
//
#include <hip/hip_runtime.h>

// Problem constants: x [4, 64, 64, 128] fp32
constexpr int C       = 128;
constexpr int N       = 4096;
constexpr int BATCH   = 4;
constexpr int TOTROWS = BATCH * N;            // 16384
constexpr float SCALE = 0.08838834764831845f; // 1/sqrt(128)
constexpr float LOG2E = 1.44269504088896340736f;

constexpr int BK   = 64;     // keys per iteration
constexpr int KSTR = 132;    // K-tile LDS stride
constexpr int VSTR = 68;     // V-tile LDS stride
constexpr int PSTR = 72;     // P-tile stride (shared 128-row P)
// attn LDS: 64*132*2 + 128*68*2 + 128*72*2 + 2*128*4 = 53760 B -> 2 blocks/CU

typedef __attribute__((ext_vector_type(8))) short        bf16x8;
typedef __attribute__((ext_vector_type(4))) float        f32x4;
typedef __attribute__((ext_vector_type(2))) unsigned int u32x2;

__device__ inline unsigned short f2bf(float f) {   // RNE float->bf16
    unsigned int u = __float_as_uint(f);
    return (unsigned short)((u + 0x7FFFu + ((u >> 16) & 1u)) >> 16);
}
__device__ inline unsigned int pack2bf(float a, float b) {
    return (unsigned int)f2bf(a) | ((unsigned int)f2bf(b) << 16);
}
__device__ inline float bf2f(unsigned int u) {
    return __uint_as_float(u << 16);
}

// ---------------------------------------------------------------------------
// QKV GEMM with in-block W transpose (fused wprep). grid (TOTROWS/64, 3),
// block 256 (4 waves, wave owns 16 rows). W fp32 L2-hot across blocks.
// q is pre-scaled by SCALE*LOG2E so attn can use exp2f (bare v_exp_f32).
// vt stored TILED: vt[b][n/64][c][n%64].
// ---------------------------------------------------------------------------
__global__ __launch_bounds__(256)
void qkv_kernel(const float* __restrict__ x,
                const float* __restrict__ Wq, const float* __restrict__ bq,
                const float* __restrict__ Wk, const float* __restrict__ bk,
                const float* __restrict__ Wv, const float* __restrict__ bv,
                unsigned short* __restrict__ qo,
                unsigned short* __restrict__ ko,
                unsigned short* __restrict__ vt)
{
    constexpr int TS = 136;
    __shared__ __align__(16) unsigned short wl[128 * TS];   // 34816 B

    const int tid  = threadIdx.x;
    const int wv   = tid >> 6;
    const int lane = tid & 63;
    const int lo   = lane & 15;
    const int quad = lane >> 4;
    const int mat  = blockIdx.y;
    const long rowbase = (long)blockIdx.x * 64 + wv * 16;

    const float* W    = (mat == 0) ? Wq : (mat == 1) ? Wk : Wv;
    const float* bias = (mat == 0) ? bq : (mat == 1) ? bk : bv;
    const float  s    = (mat == 0) ? SCALE * LOG2E : 1.0f;

    // x fragments (row = rowbase+lo, k = ks*32+quad*8), fp32->bf16 in regs.
    bf16x8 xf[4];
    {
        const float4* xr = reinterpret_cast<const float4*>(&x[(rowbase + lo) * C]);
        #pragma unroll
        for (int ks = 0; ks < 4; ++ks) {
            float4 a  = xr[ks * 8 + quad * 2];
            float4 b2 = xr[ks * 8 + quad * 2 + 1];
            union { bf16x8 v; unsigned int u[4]; } cv;
            cv.u[0] = pack2bf(a.x, a.y);
            cv.u[1] = pack2bf(a.z, a.w);
            cv.u[2] = pack2bf(b2.x, b2.y);
            cv.u[3] = pack2bf(b2.z, b2.w);
            xf[ks] = cv.v;
        }
    }

    // transpose W (fp32 row-major [i][o]) -> wl[o][i] bf16, scaled
    #pragma unroll
    for (int g = 0; g < 16; ++g) {
        int idx = g * 256 + tid;
        int i = idx >> 5, c4 = (idx & 31) * 4;
        float4 a = *reinterpret_cast<const float4*>(&W[i * 128 + c4]);
        wl[(c4 + 0) * TS + i] = f2bf(a.x * s);
        wl[(c4 + 1) * TS + i] = f2bf(a.y * s);
        wl[(c4 + 2) * TS + i] = f2bf(a.z * s);
        wl[(c4 + 3) * TS + i] = f2bf(a.w * s);
    }
    __syncthreads();

    if (mat < 2) {
        // q/k: D[m=outchan][n=row], A=wl, B=xf -> row-major store
        f32x4 acc[8] = {};
        #pragma unroll
        for (int ks = 0; ks < 4; ++ks)
            #pragma unroll
            for (int mt = 0; mt < 8; ++mt) {
                bf16x8 wf = *reinterpret_cast<const bf16x8*>(
                    &wl[(mt * 16 + lo) * TS + ks * 32 + quad * 8]);
                acc[mt] = __builtin_amdgcn_mfma_f32_16x16x32_bf16(
                    wf, xf[ks], acc[mt], 0, 0, 0);
            }
        unsigned short* out = (mat == 0) ? qo : ko;
        long row = rowbase + lo;
        #pragma unroll
        for (int mt = 0; mt < 8; ++mt) {
            float4 bb = *reinterpret_cast<const float4*>(&bias[mt * 16 + quad * 4]);
            u32x2 w;
            w[0] = pack2bf(acc[mt][0] + bb.x * s, acc[mt][1] + bb.y * s);
            w[1] = pack2bf(acc[mt][2] + bb.z * s, acc[mt][3] + bb.w * s);
            *reinterpret_cast<u32x2*>(&out[row * C + mt * 16 + quad * 4]) = w;
        }
    } else {
        // v: D[m=row][n=chan], A=xf, B=wl -> tiled transposed store
        f32x4 acc[8] = {};
        #pragma unroll
        for (int ks = 0; ks < 4; ++ks)
            #pragma unroll
            for (int ct = 0; ct < 8; ++ct) {
                bf16x8 wf = *reinterpret_cast<const bf16x8*>(
                    &wl[(ct * 16 + lo) * TS + ks * 32 + quad * 8]);
                acc[ct] = __builtin_amdgcn_mfma_f32_16x16x32_bf16(
                    xf[ks], wf, acc[ct], 0, 0, 0);
            }
        const int b = (int)(rowbase >> 12);
        const int nbase = (int)(rowbase & (N - 1));
        const int n0   = nbase + quad * 4;
        const int nblk = n0 >> 6;
        #pragma unroll
        for (int ct = 0; ct < 8; ++ct) {
            int chan = ct * 16 + lo;
            float bb = bias[chan];
            u32x2 w;
            w[0] = pack2bf(acc[ct][0] + bb, acc[ct][1] + bb);
            w[1] = pack2bf(acc[ct][2] + bb, acc[ct][3] + bb);
            *reinterpret_cast<u32x2*>(
                &vt[(((size_t)b * 64 + nblk) * 128 + chan) * 64 + (n0 & 63)]) = w;
        }
    }
}

// ---------------------------------------------------------------------------
// Flash attention, round-15: SPLIT-WORK WAVES to halve LDS-read traffic.
// r1 post-mortem: kernel runs at ~97% of ds_read_b128 throughput (544 b128
// reads/CU-iter x 12cy ~= measured 3940 cyc/block-iter); each LDS fragment
// read fed exactly ONE MFMA. This version restores 2x fragment reuse at
// 8 waves (4/SIMD): wave (wr,wh), wr=wv&3, wh=wv>>2:
//   QK^T  key-split : wave does S[keys wh*32..+32][rows wr*32..+32]
//                     -> 8 kf reads feed 16 MFMAs (kf reused across nt=2)
//   PV   chan-split : wave does O^T[chans wh*64..+64][rows wr*32..+32],
//                     all 64 keys -> 8 vf + 4 pf reads feed 16 MFMAs
// P is block-shared pl[128][PSTR] (one extra __syncthreads per iter: P
// written by (wr,0/1) pair, read by both). O chans disjoint per wh -> no
// cross-wave O reduce; l reduced via 1KB lred at the end.
// LDS reads/block-iter: 160 b128 (was 272). ot[2][4]=32 VGPR -> fits
// __launch_bounds__(512,4). Fixed-max softmax unchanged (q pre-scaled).
// ---------------------------------------------------------------------------
__global__ __launch_bounds__(512, 4)
void attn_kernel(const unsigned short* __restrict__ q,
                 const unsigned short* __restrict__ k,
                 const unsigned short* __restrict__ vt,
                 unsigned short* __restrict__ opart,
                 float* __restrict__ lpart)
{
    __shared__ __align__(16) unsigned short kl[BK * KSTR];      // 16896 B
    __shared__ __align__(16) unsigned short vl[C * VSTR];       // 17408 B
    __shared__ __align__(16) unsigned short pl[128 * PSTR];     // 18432 B
    __shared__ float lred[2 * 128];                             //  1024 B

    const int tid  = threadIdx.x;
    const int wv   = tid >> 6;          // 0..7
    const int lane = tid & 63;
    const int lo   = lane & 15;
    const int quad = lane >> 4;
    const int wr   = wv & 3;            // row group (32 q-rows)
    const int wh   = wv >> 2;           // half index (keys for QK, chans for PV)

    const int nspl = (int)(gridDim.x >> 7);      // 512 -> 4, 256 -> 2
    const int id   = blockIdx.x;
    int b, sl, qt;
    if (nspl == 4) {         // id%8 = b*2 + (sl&1)
        b  = (id >> 1) & 3;
        sl = (id & 1) | (((id >> 3) & 1) << 1);
        qt = id >> 4;        // 0..31
    } else {                 // nspl == 2
        b  = (id >> 1) & 3;
        sl = id & 1;
        qt = id >> 3;        // 0..31
    }
    const int NIT  = (N / nspl) / BK;
    const int koff = sl * (N / nspl);

    const size_t qrow0 = (size_t)b * N + qt * 128 + wr * 32;   // wave's row base
    const int    rloc0 = wr * 32;                              // local row base
    const unsigned short* kb  = k  + ((size_t)b * N + koff) * C;
    const unsigned short* vtb = vt + ((size_t)b * 64 + (koff >> 6)) * (size_t)(128 * 64);
    const int khbase = wh * 32;     // QK: this wave's key half
    const int chbase = wh * 64;     // PV: this wave's chan half

    // Q fragments (B operand): qf[nt][ks], row = qrow0 + nt*16 + lo
    bf16x8 qf[2][4];
    #pragma unroll
    for (int nt = 0; nt < 2; ++nt)
        #pragma unroll
        for (int ks = 0; ks < 4; ++ks)
            qf[nt][ks] = *reinterpret_cast<const bf16x8*>(
                &q[(qrow0 + nt * 16 + lo) * C + ks * 32 + quad * 8]);

    // staging offsets (kt-invariant): 512 threads cover 8 consecutive elems x2
    int gK[2], lK[2], gV[2], lV[2];
    #pragma unroll
    for (int t = 0; t < 2; ++t) {
        int e = t * 4096 + tid * 8;
        gK[t] = e;  lK[t] = (e >> 7) * KSTR + (e & 127);
        gV[t] = e;  lV[t] = (e >> 6) * VSTR + (e & 63);
    }
    // prefetch tile 0 into regs
    uint4 kreg[2], vreg[2];
    #pragma unroll
    for (int t = 0; t < 2; ++t) {
        kreg[t] = *reinterpret_cast<const uint4*>(&kb[gK[t]]);
        vreg[t] = *reinterpret_cast<const uint4*>(&vtb[gV[t]]);
    }

    float l_i[2] = { 0.f, 0.f };  // per-lane partial row sums (this key-half)
    // O^T accumulators: ot[nt][ct]: col = qrow0+nt*16+lo,
    //                   regs = chan chbase + ct*16 + quad*4 + r
    f32x4 ot[2][4] = {};

    for (int kt = 0; kt < NIT; ++kt) {
        __syncthreads();   // all waves done reading kl/vl/pl of prev iter
        #pragma unroll
        for (int t = 0; t < 2; ++t)
            *reinterpret_cast<uint4*>(&kl[lK[t]]) = kreg[t];
        #pragma unroll
        for (int t = 0; t < 2; ++t)
            *reinterpret_cast<uint4*>(&vl[lV[t]]) = vreg[t];
        __syncthreads();
        if (kt + 1 < NIT) {   // prefetch next tile (full iter of slack)
            const unsigned short* kn = kb  + (size_t)(kt + 1) * BK * C;
            const unsigned short* vn = vtb + (size_t)(kt + 1) * (128 * 64);
            #pragma unroll
            for (int t = 0; t < 2; ++t) {
                kreg[t] = *reinterpret_cast<const uint4*>(&kn[gK[t]]);
                vreg[t] = *reinterpret_cast<const uint4*>(&vn[gV[t]]);
            }
        }

        // ---- S^T = K.Q^T (key-split): st[mt][nt],
        //      key = khbase + mt*16 + quad*4 + r, qrow = rloc0 + nt*16 + lo
        f32x4 st[2][2] = {};
        #pragma unroll
        for (int ks = 0; ks < 4; ++ks)
            #pragma unroll
            for (int mt = 0; mt < 2; ++mt) {
                bf16x8 kf = *reinterpret_cast<const bf16x8*>(
                    &kl[(khbase + mt * 16 + lo) * KSTR + ks * 32 + quad * 8]);
                #pragma unroll
                for (int nt = 0; nt < 2; ++nt)
                    st[mt][nt] = __builtin_amdgcn_mfma_f32_16x16x32_bf16(
                        kf, qf[nt][ks], st[mt][nt], 0, 0, 0);
            }

        // ---- softmax numerator, fixed m=0: p = 2^s (s pre-scaled) ----
        #pragma unroll
        for (int nt = 0; nt < 2; ++nt) {
            float ps = 0.f;
            #pragma unroll
            for (int mt = 0; mt < 2; ++mt) {
                float p0 = exp2f(st[mt][nt][0]);
                float p1 = exp2f(st[mt][nt][1]);
                float p2 = exp2f(st[mt][nt][2]);
                float p3 = exp2f(st[mt][nt][3]);
                ps += (p0 + p1) + (p2 + p3);
                u32x2 w;
                w[0] = pack2bf(p0, p1);
                w[1] = pack2bf(p2, p3);
                *reinterpret_cast<u32x2*>(
                    &pl[(rloc0 + nt * 16 + lo) * PSTR + khbase + mt * 16 + quad * 4]) = w;
            }
            l_i[nt] += ps;           // per-lane partial; reduced after loop
        }

        __syncthreads();   // P complete (written by wh pair, read by both)

        // ---- O^T += V^T . P^T (chan-split, all 64 keys) ----
        #pragma unroll
        for (int ks2 = 0; ks2 < 2; ++ks2) {
            bf16x8 pf[2];
            #pragma unroll
            for (int nt = 0; nt < 2; ++nt)
                pf[nt] = *reinterpret_cast<const bf16x8*>(
                    &pl[(rloc0 + nt * 16 + lo) * PSTR + ks2 * 32 + quad * 8]);
            #pragma unroll
            for (int ct = 0; ct < 4; ++ct) {
                bf16x8 vf = *reinterpret_cast<const bf16x8*>(
                    &vl[(chbase + ct * 16 + lo) * VSTR + ks2 * 32 + quad * 8]);
                #pragma unroll
                for (int nt = 0; nt < 2; ++nt)
                    ot[nt][ct] = __builtin_amdgcn_mfma_f32_16x16x32_bf16(
                        vf, pf[nt], ot[nt][ct], 0, 0, 0);
            }
        }
    }

    // ---- l reduce: within wave over quad, then across the wh pair ----
    #pragma unroll
    for (int nt = 0; nt < 2; ++nt) {
        l_i[nt] += __shfl_xor(l_i[nt], 16);
        l_i[nt] += __shfl_xor(l_i[nt], 32);
    }
    if (quad == 0) {
        #pragma unroll
        for (int nt = 0; nt < 2; ++nt)
            lred[wh * 128 + rloc0 + nt * 16 + lo] = l_i[nt];
    }
    __syncthreads();

    // ---- epilogue: per-lane row-owned packed stores (chan half chbase) ----
    {
        unsigned short* ob = opart + (size_t)sl * TOTROWS * C;
        #pragma unroll
        for (int nt = 0; nt < 2; ++nt) {
            size_t rowg = qrow0 + nt * 16 + lo;    // this lane's q-row
            #pragma unroll
            for (int ct = 0; ct < 4; ++ct) {
                u32x2 w;
                w[0] = pack2bf(ot[nt][ct][0], ot[nt][ct][1]);
                w[1] = pack2bf(ot[nt][ct][2], ot[nt][ct][3]);
                *reinterpret_cast<u32x2*>(
                    &ob[rowg * C + chbase + ct * 16 + quad * 4]) = w;
            }
        }
    }
    if (wh == 0 && quad == 0) {
        #pragma unroll
        for (int nt = 0; nt < 2; ++nt)
            lpart[(size_t)sl * TOTROWS + qrow0 + nt * 16 + lo] =
                l_i[nt] + lred[128 + rloc0 + nt * 16 + lo];
    }
}

// ---------------------------------------------------------------------------
// Combine nspl splits + residual: out = x + (sum_j O_j) / (sum_j l_j)
// (fixed-max softmax -> no per-split weights)
// ---------------------------------------------------------------------------
__global__ __launch_bounds__(256)
void combine_kernel(const float* __restrict__ x,
                    const unsigned short* __restrict__ opart,
                    const float* __restrict__ lpart,
                    float* __restrict__ out, int nspl)
{
    int gid = blockIdx.x * 256 + threadIdx.x;     // TOTROWS*32
    int row = gid >> 5;
    int c4  = (gid & 31) * 4;

    float denom = 0.f;
    for (int j = 0; j < nspl; ++j) denom += lpart[(size_t)j * TOTROWS + row];
    float inv = 1.0f / denom;

    size_t idx = (size_t)row * C + c4;
    float a0 = 0.f, a1 = 0.f, a2 = 0.f, a3 = 0.f;
    for (int j = 0; j < nspl; ++j) {
        u32x2 o = *reinterpret_cast<const u32x2*>(
            &opart[(size_t)j * TOTROWS * C + idx]);
        a0 += bf2f(o[0] & 0xffff);
        a1 += bf2f(o[0] >> 16);
        a2 += bf2f(o[1] & 0xffff);
        a3 += bf2f(o[1] >> 16);
    }
    float4 xv = *reinterpret_cast<const float4*>(&x[idx]);
    float4 o;
    o.x = xv.x + a0 * inv;
    o.y = xv.y + a1 * inv;
    o.z = xv.z + a2 * inv;
    o.w = xv.w + a3 * inv;
    *reinterpret_cast<float4*>(&out[idx]) = o;
}

// ---------------------------------------------------------------------------
extern "C" void kernel_launch(void* const* d_in, const int* in_sizes, int n_in,
                              void* d_out, int out_size, void* d_ws, size_t ws_size,
                              hipStream_t stream)
{
    const float* x  = (const float*)d_in[0];
    const float* Wq = (const float*)d_in[1];
    const float* bq = (const float*)d_in[2];
    const float* Wk = (const float*)d_in[3];
    const float* bk = (const float*)d_in[4];
    const float* Wv = (const float*)d_in[5];
    const float* bv = (const float*)d_in[6];
    float* out = (float*)d_out;

    // nspl=4 needs ~29 MB of ws; fall back to 2 if the workspace is small.
    const int nspl = (ws_size >= ((size_t)31 << 20)) ? 4 : 2;

    const size_t SPLIT_BYTES = (size_t)TOTROWS * C * 2;   // 4 MB
    char* ws = (char*)d_ws;
    unsigned short* opart = (unsigned short*)ws;                  // nspl*4 MB
    char* base = ws + (size_t)nspl * SPLIT_BYTES;
    unsigned short* q  = (unsigned short*)(base);                    // 4 MB
    unsigned short* k  = (unsigned short*)(base + SPLIT_BYTES);      // 4 MB
    unsigned short* vt = (unsigned short*)(base + 2 * SPLIT_BYTES);  // 4 MB (tiled)
    float*          lp = (float*)(base + 3 * SPLIT_BYTES);           // nspl*64 KB

    qkv_kernel<<<dim3(TOTROWS / 64, 3), 256, 0, stream>>>(
        x, Wq, bq, Wk, bk, Wv, bv, q, k, vt);
    attn_kernel<<<nspl * 128, 512, 0, stream>>>(q, k, vt, opart, lp);
    combine_kernel<<<TOTROWS * 32 / 256, 256, 0, stream>>>(x, opart, lp, out, nspl);
}

// Round 3
// 133.080 us; speedup vs baseline: 1.4331x; 1.4331x over previous
//
#include <hip/hip_runtime.h>

// Problem constants: x [4, 64, 64, 128] fp32
constexpr int C       = 128;
constexpr int N       = 4096;
constexpr int BATCH   = 4;
constexpr int TOTROWS = BATCH * N;            // 16384
constexpr float SCALE = 0.08838834764831845f; // 1/sqrt(128)
constexpr float LOG2E = 1.44269504088896340736f;

constexpr int BK = 64;     // keys per iteration

typedef __attribute__((ext_vector_type(8))) short        bf16x8;
typedef __attribute__((ext_vector_type(4))) float        f32x4;
typedef __attribute__((ext_vector_type(2))) unsigned int u32x2;

__device__ inline unsigned short f2bf(float f) {   // RNE float->bf16 (scalar)
    unsigned int u = __float_as_uint(f);
    return (unsigned short)((u + 0x7FFFu + ((u >> 16) & 1u)) >> 16);
}
// packed RNE f32x2 -> bf16x2 in ONE instruction (replaces ~11-op manual pack)
__device__ inline unsigned int cvtpk(float a, float b) {
    unsigned int r;
    asm("v_cvt_pk_bf16_f32 %0, %1, %2" : "=v"(r) : "v"(a), "v"(b));
    return r;
}
__device__ inline float bf2f(unsigned int u) {
    return __uint_as_float(u << 16);
}
// bare v_exp_f32 (q is pre-scaled by LOG2E; no OCML range-fixup needed)
__device__ inline float fexp2(float x) {
#if __has_builtin(__builtin_amdgcn_exp2f)
    return __builtin_amdgcn_exp2f(x);
#else
    float r; asm("v_exp_f32 %0, %1\n\ts_nop 0" : "=v"(r) : "v"(x)); return r;
#endif
}
// async global->LDS DMA, 16B per lane; LDS dest = wave-uniform base + lane*16
__device__ inline void dma16(const void* g, void* l) {
    __builtin_amdgcn_global_load_lds(
        (const __attribute__((address_space(1))) void*)g,
        (__attribute__((address_space(3))) void*)l, 16, 0, 0);
}

// ---------------------------------------------------------------------------
// QKV GEMM with in-block W transpose. grid (TOTROWS/64, 3), block 256.
// q pre-scaled by SCALE*LOG2E. vt stored TILED: vt[b][n/64][c][n%64].
// pack2bf -> v_cvt_pk_bf16_f32 (same RNE, 1 instr).
// ---------------------------------------------------------------------------
__global__ __launch_bounds__(256)
void qkv_kernel(const float* __restrict__ x,
                const float* __restrict__ Wq, const float* __restrict__ bq,
                const float* __restrict__ Wk, const float* __restrict__ bk,
                const float* __restrict__ Wv, const float* __restrict__ bv,
                unsigned short* __restrict__ qo,
                unsigned short* __restrict__ ko,
                unsigned short* __restrict__ vt)
{
    constexpr int TS = 136;
    __shared__ __align__(16) unsigned short wl[128 * TS];   // 34816 B

    const int tid  = threadIdx.x;
    const int wv   = tid >> 6;
    const int lane = tid & 63;
    const int lo   = lane & 15;
    const int quad = lane >> 4;
    const int mat  = blockIdx.y;
    const long rowbase = (long)blockIdx.x * 64 + wv * 16;

    const float* W    = (mat == 0) ? Wq : (mat == 1) ? Wk : Wv;
    const float* bias = (mat == 0) ? bq : (mat == 1) ? bk : bv;
    const float  s    = (mat == 0) ? SCALE * LOG2E : 1.0f;

    bf16x8 xf[4];
    {
        const float4* xr = reinterpret_cast<const float4*>(&x[(rowbase + lo) * C]);
        #pragma unroll
        for (int ks = 0; ks < 4; ++ks) {
            float4 a  = xr[ks * 8 + quad * 2];
            float4 b2 = xr[ks * 8 + quad * 2 + 1];
            union { bf16x8 v; unsigned int u[4]; } cv;
            cv.u[0] = cvtpk(a.x, a.y);
            cv.u[1] = cvtpk(a.z, a.w);
            cv.u[2] = cvtpk(b2.x, b2.y);
            cv.u[3] = cvtpk(b2.z, b2.w);
            xf[ks] = cv.v;
        }
    }

    #pragma unroll
    for (int g = 0; g < 16; ++g) {
        int idx = g * 256 + tid;
        int i = idx >> 5, c4 = (idx & 31) * 4;
        float4 a = *reinterpret_cast<const float4*>(&W[i * 128 + c4]);
        wl[(c4 + 0) * TS + i] = f2bf(a.x * s);
        wl[(c4 + 1) * TS + i] = f2bf(a.y * s);
        wl[(c4 + 2) * TS + i] = f2bf(a.z * s);
        wl[(c4 + 3) * TS + i] = f2bf(a.w * s);
    }
    __syncthreads();

    if (mat < 2) {
        f32x4 acc[8] = {};
        #pragma unroll
        for (int ks = 0; ks < 4; ++ks)
            #pragma unroll
            for (int mt = 0; mt < 8; ++mt) {
                bf16x8 wf = *reinterpret_cast<const bf16x8*>(
                    &wl[(mt * 16 + lo) * TS + ks * 32 + quad * 8]);
                acc[mt] = __builtin_amdgcn_mfma_f32_16x16x32_bf16(
                    wf, xf[ks], acc[mt], 0, 0, 0);
            }
        unsigned short* out = (mat == 0) ? qo : ko;
        long row = rowbase + lo;
        #pragma unroll
        for (int mt = 0; mt < 8; ++mt) {
            float4 bb = *reinterpret_cast<const float4*>(&bias[mt * 16 + quad * 4]);
            u32x2 w;
            w[0] = cvtpk(acc[mt][0] + bb.x * s, acc[mt][1] + bb.y * s);
            w[1] = cvtpk(acc[mt][2] + bb.z * s, acc[mt][3] + bb.w * s);
            *reinterpret_cast<u32x2*>(&out[row * C + mt * 16 + quad * 4]) = w;
        }
    } else {
        f32x4 acc[8] = {};
        #pragma unroll
        for (int ks = 0; ks < 4; ++ks)
            #pragma unroll
            for (int ct = 0; ct < 8; ++ct) {
                bf16x8 wf = *reinterpret_cast<const bf16x8*>(
                    &wl[(ct * 16 + lo) * TS + ks * 32 + quad * 8]);
                acc[ct] = __builtin_amdgcn_mfma_f32_16x16x32_bf16(
                    xf[ks], wf, acc[ct], 0, 0, 0);
            }
        const int b = (int)(rowbase >> 12);
        const int nbase = (int)(rowbase & (N - 1));
        const int n0   = nbase + quad * 4;
        const int nblk = n0 >> 6;
        #pragma unroll
        for (int ct = 0; ct < 8; ++ct) {
            int chan = ct * 16 + lo;
            float bb = bias[chan];
            u32x2 w;
            w[0] = cvtpk(acc[ct][0] + bb, acc[ct][1] + bb);
            w[1] = cvtpk(acc[ct][2] + bb, acc[ct][3] + bb);
            *reinterpret_cast<u32x2*>(
                &vt[(((size_t)b * 64 + nblk) * 128 + chan) * 64 + (n0 & 63)]) = w;
        }
    }
}

// ---------------------------------------------------------------------------
// Flash attention, round-16: ASYNC-DMA 2-PHASE PIPELINE.
// r2 post-mortem: 15,750 cyc/block-iter with no pipe >50% busy -> the
// barrier-lockstep structure serializes phases; softmax was ~450 VALU
// instrs/wave-iter (manual RNE pack + OCML exp2f); epilogue 8B stores were
// written back at 64B sectors (WRITE_SIZE = 8 x opart = 126 MB).
// This version:
//  - global_load_lds DMA staging (no staging VGPRs/VALU; loads in flight
//    across the whole compute phase, drained by the single barrier/iter)
//  - K and V double-buffered in SEPARATE __shared__ objects (smA/smB) so
//    the compiler can overlap DMA(other buf) with ds_reads(current buf)
//  - XOR-swizzled unpadded K/V/P tiles (granule ^= row&7 / row&3): DMA
//    needs linear dests; swizzle applied on global src + LDS reads
//  - wave-private in-LDS P (32-key halves, no cross-wave barrier)
//  - softmax: bare v_exp_f32 + v_cvt_pk_bf16_f32 (~90 VALU/wave-iter)
//  - coalesced epilogue via LDS bounce: full 128B stores per lane
// Block 256 thr (4 waves x 32 rows, nt=2), LDS 75,904 B -> 2 blocks/CU.
// ONE __syncthreads per iteration.
// ---------------------------------------------------------------------------
__global__ __launch_bounds__(256, 2)
void attn_kernel(const unsigned short* __restrict__ q,
                 const unsigned short* __restrict__ k,
                 const unsigned short* __restrict__ vt,
                 unsigned short* __restrict__ opart,
                 float* __restrict__ lpart)
{
    // buffer A: K0 @0 (8192), V0 @8192 (8192), pad to 17472 shorts;
    //           reused as O-bounce (128 x 136 shorts) in the epilogue
    __shared__ __align__(16) unsigned short smA[17472];  // 34944 B
    __shared__ __align__(16) unsigned short smB[16384];  // 32768 B (K1,V1)
    __shared__ __align__(16) unsigned short smP[4096];   //  8192 B (4 waves x 32x32)

    const int tid  = threadIdx.x;
    const int wv   = tid >> 6;          // 0..3
    const int lane = tid & 63;
    const int lo   = lane & 15;
    const int quad = lane >> 4;

    const int nspl = (int)(gridDim.x >> 7);      // 512 -> 4, 256 -> 2
    const int id   = blockIdx.x;
    int b, sl, qt;
    if (nspl == 4) {         // id%8 = b*2 + (sl&1): pins (batch,parity) to XCD
        b  = (id >> 1) & 3;
        sl = (id & 1) | (((id >> 3) & 1) << 1);
        qt = id >> 4;        // 0..31
    } else {
        b  = (id >> 1) & 3;
        sl = id & 1;
        qt = id >> 3;
    }
    const int NIT  = (N / nspl) / BK;            // 16 (nspl=4), even
    const int koff = sl * (N / nspl);

    const int    rowb  = b * N + qt * 128;       // block's first q-row (global)
    const size_t qrow0 = (size_t)rowb + wv * 32; // wave's first q-row
    const unsigned short* kb  = k  + ((size_t)b * N + koff) * C;
    const unsigned short* vtb = vt + ((size_t)b * 64 + (koff >> 6)) * (size_t)(128 * 64);
    const char* kb8 = (const char*)kb;
    const char* vb8 = (const char*)vtb;

    unsigned short* PW = smP + wv * 1024;        // wave-private 32x32 P tile

    // Q fragments (B operand): qf[nt][ks], row = qrow0 + nt*16 + lo
    bf16x8 qf[2][4];
    #pragma unroll
    for (int nt = 0; nt < 2; ++nt)
        #pragma unroll
        for (int ks = 0; ks < 4; ++ks)
            qf[nt][ks] = *reinterpret_cast<const bf16x8*>(
                &q[(qrow0 + nt * 16 + lo) * C + ks * 32 + quad * 8]);

    // DMA source offsets (bytes, kt-invariant), pre-swizzled so that linear
    // LDS granule G holds global granule (G&mask)^(row&7) of row G>>shift.
    int offK[4], offV[4];
    #pragma unroll
    for (int c = 0; c < 4; ++c) {
        int G  = (wv * 4 + c) * 64 + lane;
        int kr = G >> 4;                              // K: 64 rows x 16 granules
        offK[c] = kr * 256 + (((G & 15) ^ (kr & 7)) << 4);
        int vr = G >> 3;                              // V: 128 rows x 8 granules
        offV[c] = vr * 128 + (((G & 7) ^ (vr & 7)) << 4);
    }

    auto stage = [&](int kt, unsigned short* dstKV) {
        const char* kt8 = kb8 + kt * 16384;
        const char* vt8 = vb8 + kt * 16384;
        #pragma unroll
        for (int c = 0; c < 4; ++c)
            dma16(kt8 + offK[c], dstKV + (wv * 4 + c) * 512);
        #pragma unroll
        for (int c = 0; c < 4; ++c)
            dma16(vt8 + offV[c], dstKV + 8192 + (wv * 4 + c) * 512);
    };

    float l_i[2] = { 0.f, 0.f };
    f32x4 ot[2][8] = {};   // O^T: col = qrow nt*16+lo, regs = chan ct*16+quad*4+r

    auto body = [&](const unsigned short* base) {
        const unsigned short* kc = base;
        const unsigned short* vc = base + 8192;

        // ---- S^T = K.Q^T : st[mt][nt], key = mt*16+quad*4+r, qrow = nt*16+lo
        f32x4 st[4][2] = {};
        #pragma unroll
        for (int ks = 0; ks < 4; ++ks)
            #pragma unroll
            for (int mt = 0; mt < 4; ++mt) {
                const bf16x8 kf = *reinterpret_cast<const bf16x8*>(
                    &kc[(mt * 16 + lo) * 128 + (((ks * 4 + quad) ^ (lo & 7)) << 3)]);
                #pragma unroll
                for (int nt = 0; nt < 2; ++nt)
                    st[mt][nt] = __builtin_amdgcn_mfma_f32_16x16x32_bf16(
                        kf, qf[nt][ks], st[mt][nt], 0, 0, 0);
            }

        // ---- per 32-key half: softmax numerator (fixed m=0) + PV ----
        #pragma unroll
        for (int h = 0; h < 2; ++h) {
            #pragma unroll
            for (int nt = 0; nt < 2; ++nt) {
                const int prow = nt * 16 + lo;
                float ps = 0.f;
                #pragma unroll
                for (int m = 0; m < 2; ++m) {
                    f32x4 s = st[2 * h + m][nt];
                    float p0 = fexp2(s[0]);
                    float p1 = fexp2(s[1]);
                    float p2 = fexp2(s[2]);
                    float p3 = fexp2(s[3]);
                    ps += (p0 + p1) + (p2 + p3);
                    u32x2 w;
                    w[0] = cvtpk(p0, p1);
                    w[1] = cvtpk(p2, p3);
                    *reinterpret_cast<u32x2*>(
                        &PW[prow * 32 + (((2 * m + (quad >> 1)) ^ (prow & 3)) << 3)
                            + (quad & 1) * 4]) = w;
                }
                l_i[nt] += ps;
            }
            bf16x8 pf[2];
            #pragma unroll
            for (int nt = 0; nt < 2; ++nt) {
                const int prow = nt * 16 + lo;
                pf[nt] = *reinterpret_cast<const bf16x8*>(
                    &PW[prow * 32 + ((quad ^ (prow & 3)) << 3)]);
            }
            #pragma unroll
            for (int ct = 0; ct < 8; ++ct) {
                const bf16x8 vf = *reinterpret_cast<const bf16x8*>(
                    &vc[(ct * 16 + lo) * 64 + (((h * 4 + quad) ^ (lo & 7)) << 3)]);
                #pragma unroll
                for (int nt = 0; nt < 2; ++nt)
                    ot[nt][ct] = __builtin_amdgcn_mfma_f32_16x16x32_bf16(
                        vf, pf[nt], ot[nt][ct], 0, 0, 0);
            }
        }
    };

    // ---- pipeline: stage next tile (async DMA) || compute current ----
    stage(0, smA);
    __syncthreads();                         // barrier drains DMA (vmcnt 0)
    for (int kt = 0; kt < NIT; kt += 2) {
        stage(kt + 1, smB);                  // kt+1 <= NIT-1 (NIT even)
        body(smA);
        __syncthreads();
        if (kt + 2 < NIT) stage(kt + 2, smA);
        body(smB);
        __syncthreads();
    }

    // ---- row-sum reduce ----
    #pragma unroll
    for (int nt = 0; nt < 2; ++nt) {
        l_i[nt] += __shfl_xor(l_i[nt], 16);
        l_i[nt] += __shfl_xor(l_i[nt], 32);
    }
    if (quad == 0) {
        #pragma unroll
        for (int nt = 0; nt < 2; ++nt)
            lpart[(size_t)sl * TOTROWS + qrow0 + nt * 16 + lo] = l_i[nt];
    }

    // ---- coalesced epilogue: bounce O through freed LDS, full-line stores
    constexpr int OSTR = 136;                // 272 B rows (16B-aligned)
    unsigned short* obl = smA;               // 128 x 136 shorts = 34816 B
    #pragma unroll
    for (int nt = 0; nt < 2; ++nt) {
        const int row = wv * 32 + nt * 16 + lo;
        #pragma unroll
        for (int ct = 0; ct < 8; ++ct) {
            u32x2 w;
            w[0] = cvtpk(ot[nt][ct][0], ot[nt][ct][1]);
            w[1] = cvtpk(ot[nt][ct][2], ot[nt][ct][3]);
            *reinterpret_cast<u32x2*>(&obl[row * OSTR + ct * 16 + quad * 4]) = w;
        }
    }
    __syncthreads();
    {
        unsigned short* obg = opart + (size_t)sl * TOTROWS * C;
        const int row  = tid >> 1;
        const int half = tid & 1;
        const unsigned short* src = &obl[row * OSTR + half * 64];
        unsigned short*       dst = &obg[((size_t)rowb + row) * C + half * 64];
        #pragma unroll
        for (int i = 0; i < 8; ++i)
            *reinterpret_cast<uint4*>(&dst[i * 8]) =
                *reinterpret_cast<const uint4*>(&src[i * 8]);
    }
}

// ---------------------------------------------------------------------------
// Combine nspl splits + residual: out = x + (sum_j O_j) / (sum_j l_j)
// ---------------------------------------------------------------------------
__global__ __launch_bounds__(256)
void combine_kernel(const float* __restrict__ x,
                    const unsigned short* __restrict__ opart,
                    const float* __restrict__ lpart,
                    float* __restrict__ out, int nspl)
{
    int gid = blockIdx.x * 256 + threadIdx.x;     // TOTROWS*32
    int row = gid >> 5;
    int c4  = (gid & 31) * 4;

    float denom = 0.f;
    for (int j = 0; j < nspl; ++j) denom += lpart[(size_t)j * TOTROWS + row];
    float inv = 1.0f / denom;

    size_t idx = (size_t)row * C + c4;
    float a0 = 0.f, a1 = 0.f, a2 = 0.f, a3 = 0.f;
    for (int j = 0; j < nspl; ++j) {
        u32x2 o = *reinterpret_cast<const u32x2*>(
            &opart[(size_t)j * TOTROWS * C + idx]);
        a0 += bf2f(o[0] & 0xffff);
        a1 += bf2f(o[0] >> 16);
        a2 += bf2f(o[1] & 0xffff);
        a3 += bf2f(o[1] >> 16);
    }
    float4 xv = *reinterpret_cast<const float4*>(&x[idx]);
    float4 o;
    o.x = xv.x + a0 * inv;
    o.y = xv.y + a1 * inv;
    o.z = xv.z + a2 * inv;
    o.w = xv.w + a3 * inv;
    *reinterpret_cast<float4*>(&out[idx]) = o;
}

// ---------------------------------------------------------------------------
extern "C" void kernel_launch(void* const* d_in, const int* in_sizes, int n_in,
                              void* d_out, int out_size, void* d_ws, size_t ws_size,
                              hipStream_t stream)
{
    const float* x  = (const float*)d_in[0];
    const float* Wq = (const float*)d_in[1];
    const float* bq = (const float*)d_in[2];
    const float* Wk = (const float*)d_in[3];
    const float* bk = (const float*)d_in[4];
    const float* Wv = (const float*)d_in[5];
    const float* bv = (const float*)d_in[6];
    float* out = (float*)d_out;

    const int nspl = (ws_size >= ((size_t)31 << 20)) ? 4 : 2;

    const size_t SPLIT_BYTES = (size_t)TOTROWS * C * 2;   // 4 MB
    char* ws = (char*)d_ws;
    unsigned short* opart = (unsigned short*)ws;                  // nspl*4 MB
    char* base = ws + (size_t)nspl * SPLIT_BYTES;
    unsigned short* q  = (unsigned short*)(base);                    // 4 MB
    unsigned short* k  = (unsigned short*)(base + SPLIT_BYTES);      // 4 MB
    unsigned short* vt = (unsigned short*)(base + 2 * SPLIT_BYTES);  // 4 MB (tiled)
    float*          lp = (float*)(base + 3 * SPLIT_BYTES);           // nspl*64 KB

    qkv_kernel<<<dim3(TOTROWS / 64, 3), 256, 0, stream>>>(
        x, Wq, bq, Wk, bk, Wv, bv, q, k, vt);
    attn_kernel<<<nspl * 128, 256, 0, stream>>>(q, k, vt, opart, lp);
    combine_kernel<<<TOTROWS * 32 / 256, 256, 0, stream>>>(x, opart, lp, out, nspl);
}